// Round 2
// baseline (297.341 us; speedup 1.0000x reference)
//
#include <hip/hip_runtime.h>
#include <hip/hip_bf16.h>
#include <cstdint>

// Problem constants (B=4, S=2048, D2=1024, DV=64, d_k=64)
#define S_LEN 2048
#define D2_   1024
#define DV_   64
#define NB_   4

typedef __bf16 bf16x8 __attribute__((ext_vector_type(8)));
typedef float  f32x4  __attribute__((ext_vector_type(4)));

// fp32 -> bf16 round-to-nearest-even (inputs are normal floats; NaN path unused)
__device__ __forceinline__ unsigned short f2bf(float f) {
  union { float f; unsigned int u; } v; v.f = f;
  unsigned int r = v.u + 0x7fffu + ((v.u >> 16) & 1u);
  return (unsigned short)(r >> 16);
}

// async global->LDS, 16B per lane (global_load_lds_dwordx4)
__device__ __forceinline__ void async16(const unsigned short* g, unsigned short* l) {
  __builtin_amdgcn_global_load_lds(
      (__attribute__((address_space(1))) void*)g,
      (__attribute__((address_space(3))) void*)l,
      16, 0, 0);
}

// ---------------------------------------------------------------------------
// Kernel 1: LayerNorm(q) * (1/sqrt(d_k)) -> bf16.  One block per row of 1024.
// ---------------------------------------------------------------------------
__global__ void __launch_bounds__(256) ln_q_kernel(
    const float* __restrict__ q, const float* __restrict__ gam,
    const float* __restrict__ bet, unsigned short* __restrict__ qn) {
  const int row = blockIdx.x;
  const int t = threadIdx.x;
  const float4 x = ((const float4*)(q + (size_t)row * D2_))[t];
  float s  = x.x + x.y + x.z + x.w;
  float ss = x.x * x.x + x.y * x.y + x.z * x.z + x.w * x.w;
  #pragma unroll
  for (int o = 32; o > 0; o >>= 1) { s += __shfl_down(s, o); ss += __shfl_down(ss, o); }
  __shared__ float red[8];
  if ((t & 63) == 0) { red[t >> 6] = s; red[(t >> 6) + 4] = ss; }
  __syncthreads();
  const float tot  = red[0] + red[1] + red[2] + red[3];
  const float tots = red[4] + red[5] + red[6] + red[7];
  const float mu  = tot * (1.0f / D2_);
  const float var = tots * (1.0f / D2_) - mu * mu;
  const float rs  = rsqrtf(var + 1e-6f) * 0.125f;   // fold 1/sqrt(64) into LN
  const float4 gv = ((const float4*)gam)[t];
  const float4 bv = ((const float4*)bet)[t];
  ushort4 o4;
  o4.x = f2bf((x.x - mu) * rs * gv.x + 0.125f * bv.x);
  o4.y = f2bf((x.y - mu) * rs * gv.y + 0.125f * bv.y);
  o4.z = f2bf((x.z - mu) * rs * gv.z + 0.125f * bv.z);
  o4.w = f2bf((x.w - mu) * rs * gv.w + 0.125f * bv.w);
  ((ushort4*)(qn + (size_t)row * D2_))[t] = o4;
}

// ---------------------------------------------------------------------------
// Kernel 2: cast k -> bf16 (8 elements/thread)
// ---------------------------------------------------------------------------
__global__ void __launch_bounds__(256) cast_k_kernel(
    const float* __restrict__ k, unsigned short* __restrict__ kb) {
  const size_t i = ((size_t)blockIdx.x * 256 + threadIdx.x) * 8;
  const float4 a = ((const float4*)(k + i))[0];
  const float4 b = ((const float4*)(k + i))[1];
  ushort4 lo, hi;
  lo.x = f2bf(a.x); lo.y = f2bf(a.y); lo.z = f2bf(a.z); lo.w = f2bf(a.w);
  hi.x = f2bf(b.x); hi.y = f2bf(b.y); hi.z = f2bf(b.z); hi.w = f2bf(b.w);
  ((ushort4*)(kb + i))[0] = lo;
  ((ushort4*)(kb + i))[1] = hi;
}

// ---------------------------------------------------------------------------
// Kernel 3: w2[d] = sum_j V[j] * fc_w[d*64+j]   (rank-1 collapse of @fc_w.T)
// ---------------------------------------------------------------------------
__global__ void __launch_bounds__(256) w2_kernel(
    const float* __restrict__ V, const float* __restrict__ fw,
    float* __restrict__ w2) {
  const int d = blockIdx.x * 256 + threadIdx.x;
  const float4* r  = (const float4*)(fw + (size_t)d * DV_);
  const float4* vv = (const float4*)V;
  float s = 0.f;
  #pragma unroll
  for (int j = 0; j < 16; ++j) {
    const float4 a = r[j], b = vv[j];
    s += a.x * b.x + a.y * b.y + a.z * b.z + a.w * b.w;
  }
  w2[d] = s;
}

// ---------------------------------------------------------------------------
// Kernel 4: attn = masked( qn_bf16 @ kb_bf16^T ).  m97-structure MFMA GEMM.
// 128x128 tile, BK=32, 4 waves (each 64x64 = 4x4 frags of 16x16x32).
// ---------------------------------------------------------------------------
__global__ void __launch_bounds__(256) attn_gemm_kernel(
    const unsigned short* __restrict__ qn,   // [B*S, D2] bf16
    const unsigned short* __restrict__ kb,   // [B*S, D2] bf16
    const int* __restrict__ mask,            // [B, S, S] int32
    float* __restrict__ attn) {              // [B, S, S] f32
  __shared__ __align__(16) unsigned short Asm_[128 * 32];
  __shared__ __align__(16) unsigned short Bsm_[128 * 32];

  const int t  = threadIdx.x;
  const int bn = blockIdx.x * 128;
  const int bm = blockIdx.y * 128;
  const int bt = blockIdx.z;

  // staging: thread t loads rows (t>>2) and (t>>2)+64, col-group (t&3)*8.
  // LDS layout [row][32] contiguous => lds byte off = t*16 (+4096 for 2nd half)
  // which is exactly wave-uniform-base + lane*16 as global_load_lds requires.
  const unsigned short* gA = qn + ((size_t)bt * S_LEN + bm + (t >> 2)) * D2_ + (t & 3) * 8;
  const unsigned short* gB = kb + ((size_t)bt * S_LEN + bn + (t >> 2)) * D2_ + (t & 3) * 8;
  unsigned short* lA = Asm_ + t * 8;
  unsigned short* lB = Bsm_ + t * 8;

  const int lane = t & 63;
  const int w  = t >> 6;
  const int wm = (w >> 1) * 64;   // wave row offset in tile
  const int wn = (w & 1) * 64;    // wave col offset in tile
  const int lr = lane & 15;
  const int lg = lane >> 4;

  f32x4 acc[4][4] = {};

  for (int k0 = 0; k0 < D2_; k0 += 32) {
    async16(gA, lA);
    async16(gA + 64 * D2_, lA + 2048);
    async16(gB, lB);
    async16(gB + 64 * D2_, lB + 2048);
    gA += 32; gB += 32;
    __syncthreads();   // compiler emits vmcnt(0) drain before s_barrier
    bf16x8 af[4], bfv[4];
    #pragma unroll
    for (int f = 0; f < 4; ++f) {
      af[f]  = *(const bf16x8*)(Asm_ + (wm + f * 16 + lr) * 32 + lg * 8);
      bfv[f] = *(const bf16x8*)(Bsm_ + (wn + f * 16 + lr) * 32 + lg * 8);
    }
    #pragma unroll
    for (int fm = 0; fm < 4; ++fm)
      #pragma unroll
      for (int fn = 0; fn < 4; ++fn)
        acc[fm][fn] = __builtin_amdgcn_mfma_f32_16x16x32_bf16(
            af[fm], bfv[fn], acc[fm][fn], 0, 0, 0);
    __syncthreads();
  }

  // epilogue: C layout col=lane&15, row=(lane>>4)*4+reg  (m89-verified)
  #pragma unroll
  for (int fm = 0; fm < 4; ++fm) {
    #pragma unroll
    for (int r = 0; r < 4; ++r) {
      const int srow = bm + wm + fm * 16 + lg * 4 + r;
      const size_t off = ((size_t)bt * S_LEN + srow) * S_LEN + bn + wn;
      const int* mrow = mask + off;
      float*    arow = attn + off;
      #pragma unroll
      for (int fn = 0; fn < 4; ++fn) {
        const int c = fn * 16 + lr;
        float vv = acc[fm][fn][r];
        vv = mrow[c] ? 0.0f : vv;   // jnp.where(mask, 0, attn)
        arow[c] = vv;
      }
    }
  }
}

// ---------------------------------------------------------------------------
// Kernel 5: out[row,:] = rowsum(attn[row,:]) * w2[:] + fc_b[:] + q[row,:]
// NOTE: overwrites the out-region that temporarily held qn/kb — it reads
// nothing from that region, so this is safe under stream ordering.
// ---------------------------------------------------------------------------
__global__ void __launch_bounds__(256) out_kernel(
    const float* __restrict__ attn, const float* __restrict__ q,
    const float* __restrict__ w2, const float* __restrict__ fcb,
    float* __restrict__ out) {
  const int row = blockIdx.x;
  const int t = threadIdx.x;
  const float4* ar = (const float4*)(attn + (size_t)row * S_LEN);
  const float4 a = ar[t], b = ar[t + 256];
  float s = a.x + a.y + a.z + a.w + b.x + b.y + b.z + b.w;
  #pragma unroll
  for (int o = 32; o > 0; o >>= 1) s += __shfl_down(s, o);
  __shared__ float red[4];
  if ((t & 63) == 0) red[t >> 6] = s;
  __syncthreads();
  const float rs = red[0] + red[1] + red[2] + red[3];
  const float4 wv = ((const float4*)w2)[t];
  const float4 bv = ((const float4*)fcb)[t];
  const float4 qv = ((const float4*)(q + (size_t)row * D2_))[t];
  float4 o4;
  o4.x = rs * wv.x + bv.x + qv.x;
  o4.y = rs * wv.y + bv.y + qv.y;
  o4.z = rs * wv.z + bv.z + qv.z;
  o4.w = rs * wv.w + bv.w + qv.w;
  ((float4*)(out + (size_t)row * D2_))[t] = o4;
}

// ---------------------------------------------------------------------------
extern "C" void kernel_launch(void* const* d_in, const int* in_sizes, int n_in,
                              void* d_out, int out_size, void* d_ws, size_t ws_size,
                              hipStream_t stream) {
  (void)in_sizes; (void)n_in; (void)out_size; (void)ws_size;
  const float* q    = (const float*)d_in[0];
  const float* k    = (const float*)d_in[1];
  /* d_in[2] == v: provably unused by the reference computation */
  const int*   mask = (const int*)d_in[3];
  const float* V    = (const float*)d_in[4];
  const float* fw   = (const float*)d_in[5];
  const float* fcb  = (const float*)d_in[6];
  const float* lg   = (const float*)d_in[7];
  const float* lb   = (const float*)d_in[8];

  float* out  = (float*)d_out;                          // [B,S,D2]  32 MiB
  float* attn = out + (size_t)NB_ * S_LEN * D2_;        // [B,S,S]   64 MiB

  // Scratch plan (avoids overflowing d_ws — round-1 fix):
  //   qn/kb live INSIDE the out-region of d_out (exactly 32 MiB), which is
  //   dead until out_kernel overwrites it at the very end.
  //   d_ws holds only w2 (4 KiB).
  unsigned short* qn = (unsigned short*)out;                     // 16 MiB
  unsigned short* kb = qn + (size_t)NB_ * S_LEN * D2_;           // 16 MiB
  float* w2 = (float*)d_ws;                                      // 4 KiB

  ln_q_kernel<<<NB_ * S_LEN, 256, 0, stream>>>(q, lg, lb, qn);
  cast_k_kernel<<<(NB_ * S_LEN * D2_) / 2048, 256, 0, stream>>>(k, kb);
  w2_kernel<<<D2_ / 256, 256, 0, stream>>>(V, fw, w2);
  attn_gemm_kernel<<<dim3(S_LEN / 128, S_LEN / 128, NB_), 256, 0, stream>>>(qn, kb, mask, attn);
  out_kernel<<<NB_ * S_LEN, 256, 0, stream>>>(attn, q, w2, fcb, out);
}

// Round 3
// 295.579 us; speedup vs baseline: 1.0060x; 1.0060x over previous
//
#include <hip/hip_runtime.h>
#include <hip/hip_bf16.h>
#include <cstdint>

// Problem constants (B=4, S=2048, D2=1024, DV=64, d_k=64)
#define S_LEN 2048
#define D2_   1024
#define DV_   64
#define NB_   4

typedef __bf16 bf16x8 __attribute__((ext_vector_type(8)));
typedef float  f32x4  __attribute__((ext_vector_type(4)));

// fp32 -> bf16 round-to-nearest-even
__device__ __forceinline__ unsigned short f2bf(float f) {
  union { float f; unsigned int u; } v; v.f = f;
  unsigned int r = v.u + 0x7fffu + ((v.u >> 16) & 1u);
  return (unsigned short)(r >> 16);
}

// async global->LDS, 16B per lane (global_load_lds_dwordx4)
__device__ __forceinline__ void async16(const unsigned short* g, unsigned short* l) {
  __builtin_amdgcn_global_load_lds(
      (__attribute__((address_space(1))) void*)g,
      (__attribute__((address_space(3))) void*)l,
      16, 0, 0);
}

// ---------------------------------------------------------------------------
// Kernel 1 (fused prep): per row r:
//   qn[r,:] = bf16( LN(q[r,:]) * 0.125 )      (1/sqrt(64) folded in)
//   kb[r,:] = bf16( k[r,:] )
//   blocks 0..3 additionally: w2[d] = fc_w[d,:] . V   (rank-1 collapse)
// ---------------------------------------------------------------------------
__global__ void __launch_bounds__(256) prep_kernel(
    const float* __restrict__ q, const float* __restrict__ k,
    const float* __restrict__ gam, const float* __restrict__ bet,
    const float* __restrict__ V, const float* __restrict__ fw,
    unsigned short* __restrict__ qn, unsigned short* __restrict__ kb,
    float* __restrict__ w2) {
  const int row = blockIdx.x;
  const int t = threadIdx.x;

  // ---- LN(q) ----
  const float4 x = ((const float4*)(q + (size_t)row * D2_))[t];
  float s  = x.x + x.y + x.z + x.w;
  float ss = x.x * x.x + x.y * x.y + x.z * x.z + x.w * x.w;
  #pragma unroll
  for (int o = 32; o > 0; o >>= 1) { s += __shfl_down(s, o); ss += __shfl_down(ss, o); }
  __shared__ float red[8];
  if ((t & 63) == 0) { red[t >> 6] = s; red[(t >> 6) + 4] = ss; }
  __syncthreads();
  const float tot  = red[0] + red[1] + red[2] + red[3];
  const float tots = red[4] + red[5] + red[6] + red[7];
  const float mu  = tot * (1.0f / D2_);
  const float var = tots * (1.0f / D2_) - mu * mu;
  const float rs  = rsqrtf(var + 1e-6f) * 0.125f;
  const float4 gv = ((const float4*)gam)[t];
  const float4 bv = ((const float4*)bet)[t];
  ushort4 o4;
  o4.x = f2bf((x.x - mu) * rs * gv.x + 0.125f * bv.x);
  o4.y = f2bf((x.y - mu) * rs * gv.y + 0.125f * bv.y);
  o4.z = f2bf((x.z - mu) * rs * gv.z + 0.125f * bv.z);
  o4.w = f2bf((x.w - mu) * rs * gv.w + 0.125f * bv.w);
  ((ushort4*)(qn + (size_t)row * D2_))[t] = o4;

  // ---- cast k row (4 elems/thread) ----
  const float4 kx = ((const float4*)(k + (size_t)row * D2_))[t];
  ushort4 k4;
  k4.x = f2bf(kx.x); k4.y = f2bf(kx.y); k4.z = f2bf(kx.z); k4.w = f2bf(kx.w);
  ((ushort4*)(kb + (size_t)row * D2_))[t] = k4;

  // ---- w2 (only blocks 0..3) ----
  if (row < 4) {
    const int d = row * 256 + t;
    const float4* r  = (const float4*)(fw + (size_t)d * DV_);
    const float4* vv = (const float4*)V;
    float acc = 0.f;
    #pragma unroll
    for (int j = 0; j < 16; ++j) {
      const float4 a = r[j], b = vv[j];
      acc += a.x * b.x + a.y * b.y + a.z * b.z + a.w * b.w;
    }
    w2[d] = acc;
  }
}

// ---------------------------------------------------------------------------
// Kernel 2: attn = masked( qn_bf16 @ kb_bf16^T ).
// 128x128 tile, BK=32, 4 waves (each 64x64 = 4x4 frags of 16x16x32).
// DOUBLE-BUFFERED LDS, ONE barrier per K-iter:
//   iter i: barrier; prefetch buf[(i+1)&1]; read+MFMA buf[i&1].
//   The barrier's compiler-emitted vmcnt(0)/lgkmcnt(0) drain guarantees
//   (a) prefetch of buf[i&1] (issued in iter i-1) has landed,
//   (b) all waves finished reading buf[(i+1)&1] in iter i-1 before we
//       overwrite it. Prefetch latency overlaps the whole compute phase.
// ---------------------------------------------------------------------------
__global__ void __launch_bounds__(256) attn_gemm_kernel(
    const unsigned short* __restrict__ qn,   // [B*S, D2] bf16
    const unsigned short* __restrict__ kb,   // [B*S, D2] bf16
    const int* __restrict__ mask,            // [B, S, S] int32
    float* __restrict__ attn) {              // [B, S, S] f32
  __shared__ __align__(16) unsigned short Asm_[2][128 * 32];  // 2 x 8 KiB
  __shared__ __align__(16) unsigned short Bsm_[2][128 * 32];  // 2 x 8 KiB

  const int t  = threadIdx.x;
  const int bn = blockIdx.x * 128;
  const int bm = blockIdx.y * 128;
  const int bt = blockIdx.z;

  // staging: thread t loads rows (t>>2) and (t>>2)+64, col-group (t&3)*8.
  // LDS dest = wave-uniform base + lane*16B (global_load_lds contract).
  const unsigned short* gA = qn + ((size_t)bt * S_LEN + bm + (t >> 2)) * D2_ + (t & 3) * 8;
  const unsigned short* gB = kb + ((size_t)bt * S_LEN + bn + (t >> 2)) * D2_ + (t & 3) * 8;

  const int lane = t & 63;
  const int w  = t >> 6;
  const int wm = (w >> 1) * 64;   // wave row offset in tile
  const int wn = (w & 1) * 64;    // wave col offset in tile
  const int lr = lane & 15;
  const int lg = lane >> 4;

  f32x4 acc[4][4] = {};

  // prologue: stage buffer 0
  async16(gA, Asm_[0] + t * 8);
  async16(gA + 64 * D2_, Asm_[0] + t * 8 + 2048);
  async16(gB, Bsm_[0] + t * 8);
  async16(gB + 64 * D2_, Bsm_[0] + t * 8 + 2048);
  gA += 32; gB += 32;

  #pragma unroll 4
  for (int it = 0; it < 32; ++it) {
    __syncthreads();   // drains vmcnt (prefetch landed) + lgkmcnt (reads done)
    const unsigned short* Ac = Asm_[it & 1];
    const unsigned short* Bc = Bsm_[it & 1];
    if (it < 31) {
      unsigned short* An = Asm_[(it + 1) & 1];
      unsigned short* Bn = Bsm_[(it + 1) & 1];
      async16(gA, An + t * 8);
      async16(gA + 64 * D2_, An + t * 8 + 2048);
      async16(gB, Bn + t * 8);
      async16(gB + 64 * D2_, Bn + t * 8 + 2048);
      gA += 32; gB += 32;
    }
    bf16x8 af[4], bfv[4];
    #pragma unroll
    for (int f = 0; f < 4; ++f) {
      af[f]  = *(const bf16x8*)(Ac + (wm + f * 16 + lr) * 32 + lg * 8);
      bfv[f] = *(const bf16x8*)(Bc + (wn + f * 16 + lr) * 32 + lg * 8);
    }
    #pragma unroll
    for (int fm = 0; fm < 4; ++fm)
      #pragma unroll
      for (int fn = 0; fn < 4; ++fn)
        acc[fm][fn] = __builtin_amdgcn_mfma_f32_16x16x32_bf16(
            af[fm], bfv[fn], acc[fm][fn], 0, 0, 0);
  }

  // epilogue: C layout col=lane&15, row=(lane>>4)*4+reg  (m89-verified)
  #pragma unroll
  for (int fm = 0; fm < 4; ++fm) {
    #pragma unroll
    for (int r = 0; r < 4; ++r) {
      const int srow = bm + wm + fm * 16 + lg * 4 + r;
      const size_t off = ((size_t)bt * S_LEN + srow) * S_LEN + bn + wn;
      const int* mrow = mask + off;
      float*    arow = attn + off;
      #pragma unroll
      for (int fn = 0; fn < 4; ++fn) {
        const int c = fn * 16 + lr;
        float vv = acc[fm][fn][r];
        vv = mrow[c] ? 0.0f : vv;   // jnp.where(mask, 0, attn)
        arow[c] = vv;
      }
    }
  }
}

// ---------------------------------------------------------------------------
// Kernel 3: out[row,:] = rowsum(attn[row,:]) * w2[:] + fc_b[:] + q[row,:]
// Overwrites the out-region that temporarily held qn/kb (reads nothing
// from it — safe under stream ordering).
// ---------------------------------------------------------------------------
__global__ void __launch_bounds__(256) out_kernel(
    const float* __restrict__ attn, const float* __restrict__ q,
    const float* __restrict__ w2, const float* __restrict__ fcb,
    float* __restrict__ out) {
  const int row = blockIdx.x;
  const int t = threadIdx.x;
  const float4* ar = (const float4*)(attn + (size_t)row * S_LEN);
  const float4 a = ar[t], b = ar[t + 256];
  float s = a.x + a.y + a.z + a.w + b.x + b.y + b.z + b.w;
  #pragma unroll
  for (int o = 32; o > 0; o >>= 1) s += __shfl_down(s, o);
  __shared__ float red[4];
  if ((t & 63) == 0) red[t >> 6] = s;
  __syncthreads();
  const float rs = red[0] + red[1] + red[2] + red[3];
  const float4 wv = ((const float4*)w2)[t];
  const float4 bv = ((const float4*)fcb)[t];
  const float4 qv = ((const float4*)(q + (size_t)row * D2_))[t];
  float4 o4;
  o4.x = rs * wv.x + bv.x + qv.x;
  o4.y = rs * wv.y + bv.y + qv.y;
  o4.z = rs * wv.z + bv.z + qv.z;
  o4.w = rs * wv.w + bv.w + qv.w;
  ((float4*)(out + (size_t)row * D2_))[t] = o4;
}

// ---------------------------------------------------------------------------
extern "C" void kernel_launch(void* const* d_in, const int* in_sizes, int n_in,
                              void* d_out, int out_size, void* d_ws, size_t ws_size,
                              hipStream_t stream) {
  (void)in_sizes; (void)n_in; (void)out_size; (void)ws_size;
  const float* q    = (const float*)d_in[0];
  const float* k    = (const float*)d_in[1];
  /* d_in[2] == v: provably unused by the reference computation */
  const int*   mask = (const int*)d_in[3];
  const float* V    = (const float*)d_in[4];
  const float* fw   = (const float*)d_in[5];
  const float* fcb  = (const float*)d_in[6];
  const float* lg   = (const float*)d_in[7];
  const float* lb   = (const float*)d_in[8];

  float* out  = (float*)d_out;                          // [B,S,D2]  32 MiB
  float* attn = out + (size_t)NB_ * S_LEN * D2_;        // [B,S,S]   64 MiB

  // qn/kb live INSIDE the out-region (exactly 32 MiB), dead until out_kernel
  // overwrites it at the very end.  d_ws holds only w2 (4 KiB).
  unsigned short* qn = (unsigned short*)out;                     // 16 MiB
  unsigned short* kb = qn + (size_t)NB_ * S_LEN * D2_;           // 16 MiB
  float* w2 = (float*)d_ws;                                      // 4 KiB

  prep_kernel<<<NB_ * S_LEN, 256, 0, stream>>>(q, k, lg, lb, V, fw, qn, kb, w2);
  attn_gemm_kernel<<<dim3(S_LEN / 128, S_LEN / 128, NB_), 256, 0, stream>>>(qn, kb, mask, attn);
  out_kernel<<<NB_ * S_LEN, 256, 0, stream>>>(attn, q, w2, fcb, out);
}